// Round 5
// baseline (4157.410 us; speedup 1.0000x reference)
//
#include <hip/hip_runtime.h>
#include <cstdint>
#include <cstddef>

typedef unsigned short u16;
typedef unsigned int u32;

typedef __bf16 bf16x8 __attribute__((ext_vector_type(8)));
typedef float f32x4 __attribute__((ext_vector_type(4)));
typedef u16 u16x8 __attribute__((ext_vector_type(8)));

__device__ __forceinline__ u16 f2bf(float f) {
  union { float f; u32 u; } v; v.f = f;
  u32 r = v.u + 0x7fffu + ((v.u >> 16) & 1u);   // RNE
  return (u16)(r >> 16);
}
__device__ __forceinline__ float bf2f(u16 h) {
  union { u32 u; float f; } v; v.u = ((u32)h) << 16;
  return v.f;
}

// async global->LDS, 16B per lane; LDS dest = wave-uniform base + lane*16
__device__ __forceinline__ void gld16(const u16* g, u16* l) {
  __builtin_amdgcn_global_load_lds((const __attribute__((address_space(1))) u32*)g,
                                   (__attribute__((address_space(3))) u32*)l,
                                   16, 0, 0);
}

// ---------------------------------------------------------------------------
// GEMM core macro-structure (round-0 known-good, MfmaUtil 32%):
// 128x128 tiles, BK=32, double-buffered LDS; prefetch issued right after the
// barrier, before compute, so the vmcnt(0) drain waits on loads one full
// compute-phase old. LDS chunk swizzle: chunk(r,c) at slot r*4+(c^((r>>1)&3))
// -> 0 bank conflicts (measured).
// ---------------------------------------------------------------------------
template<bool OUT_F32>
__global__ __launch_bounds__(256)
void gemm_bt(const u16* __restrict__ A, const u16* __restrict__ Bt,
             const float* __restrict__ bias, void* __restrict__ C,
             int M, int N, int K) {
  __shared__ __attribute__((aligned(16))) u16 As[2][128*32];
  __shared__ __attribute__((aligned(16))) u16 Bs[2][128*32];
  const int tid  = threadIdx.x;
  const int lane = tid & 63;
  const int wave = tid >> 6;
  const int wm = wave >> 1, wn = wave & 1;
  const int bn = blockIdx.x * 128;
  const int bm = blockIdx.y * 128;
  const int kq = lane >> 4, ml = lane & 15;

  const u16* agp[2]; const u16* bgp[2]; int ldst[2];
#pragma unroll
  for (int j = 0; j < 2; ++j) {
    int s = wave*128 + j*64 + lane;
    int r = s >> 2;
    int c = (s & 3) ^ ((r >> 1) & 3);
    agp[j] = A  + (size_t)(bm + r)*K + c*8;
    bgp[j] = Bt + (size_t)(bn + r)*K + c*8;
    ldst[j] = (wave*128 + j*64)*8;
  }

  auto stage = [&](int p, int k0) {
#pragma unroll
    for (int j = 0; j < 2; ++j) {
      gld16(agp[j] + k0, &As[p][0] + ldst[j]);
      gld16(bgp[j] + k0, &Bs[p][0] + ldst[j]);
    }
  };

  f32x4 acc[4][4] = {};

  auto compute = [&](int p) {
    bf16x8 af[4], bfr[4];
#pragma unroll
    for (int t = 0; t < 4; ++t) {
      int ra = wm*64 + t*16 + ml;
      af[t]  = *(const bf16x8*)(&As[p][0] + (size_t)(ra*4 + (kq ^ ((ra >> 1) & 3)))*8);
      int rb = wn*64 + t*16 + ml;
      bfr[t] = *(const bf16x8*)(&Bs[p][0] + (size_t)(rb*4 + (kq ^ ((rb >> 1) & 3)))*8);
    }
#pragma unroll
    for (int i = 0; i < 4; ++i)
#pragma unroll
      for (int j = 0; j < 4; ++j)
        acc[i][j] = __builtin_amdgcn_mfma_f32_16x16x32_bf16(af[i], bfr[j], acc[i][j], 0, 0, 0);
  };

  stage(0, 0);
  for (int k0 = 0; k0 < K; k0 += 64) {          // K multiple of 64
    __syncthreads();
    if (k0 + 32 < K) stage(1, k0 + 32);
    compute(0);
    __syncthreads();
    if (k0 + 64 < K) stage(0, k0 + 64);
    compute(1);
  }

  // C/D layout: col = lane&15, row = (lane>>4)*4 + reg   [m89/m91 verified]
#pragma unroll
  for (int i = 0; i < 4; ++i) {
    int rg0 = bm + wm*64 + i*16 + kq*4;
#pragma unroll
    for (int j = 0; j < 4; ++j) {
      int cg = bn + wn*64 + j*16 + ml;
      float bv = bias[cg];
#pragma unroll
      for (int r = 0; r < 4; ++r) {
        float v = acc[i][j][r] + bv;
        if (OUT_F32) ((float*)C)[(size_t)(rg0 + r)*N + cg] = v;
        else         ((u16*)C)[(size_t)(rg0 + r)*N + cg]   = f2bf(v);
      }
    }
  }
}

// ---------------------------------------------------------------------------
// QKV GEMM with FUSED RoPE epilogue. Same main loop as gemm_bt (M=4096,
// N=5120, K=4096). Epilogue routes by block-uniform bn region:
//   cg <  4096 : q -> rope -> *QS -> qr (b,head,n,d)
//   cg <  4608 : k -> rope -> kr (b,kvh,n,d)
//   else       : v -> vbuf (4096 x 512, compact)
// RoPE pair partner (cg^1) sits in lane ml^1 -> __shfl_xor(v,1); both lanes
// of a pair compute the same angle (dp = d>>1). Bias added BEFORE rope
// (reference: rope(x@W + b)). Kills rope_q/rope_k kernels and the qkvl q/k
// round-trip (~75 MB). qr/kr/vbuf live in fresh ws regions (no aliasing with
// wqkv, which this kernel is still reading).
// ---------------------------------------------------------------------------
__global__ __launch_bounds__(256)
void gemm_qkv(const u16* __restrict__ A, const u16* __restrict__ Bt,
              const float* __restrict__ bias, u16* __restrict__ qr,
              u16* __restrict__ kr, u16* __restrict__ vbuf, int K) {
  __shared__ __attribute__((aligned(16))) u16 As[2][128*32];
  __shared__ __attribute__((aligned(16))) u16 Bs[2][128*32];
  const int tid  = threadIdx.x;
  const int lane = tid & 63;
  const int wave = tid >> 6;
  const int wm = wave >> 1, wn = wave & 1;
  const int bn = blockIdx.x * 128;
  const int bm = blockIdx.y * 128;
  const int kq = lane >> 4, ml = lane & 15;

  const u16* agp[2]; const u16* bgp[2]; int ldst[2];
#pragma unroll
  for (int j = 0; j < 2; ++j) {
    int s = wave*128 + j*64 + lane;
    int r = s >> 2;
    int c = (s & 3) ^ ((r >> 1) & 3);
    agp[j] = A  + (size_t)(bm + r)*K + c*8;
    bgp[j] = Bt + (size_t)(bn + r)*K + c*8;
    ldst[j] = (wave*128 + j*64)*8;
  }

  auto stage = [&](int p, int k0) {
#pragma unroll
    for (int j = 0; j < 2; ++j) {
      gld16(agp[j] + k0, &As[p][0] + ldst[j]);
      gld16(bgp[j] + k0, &Bs[p][0] + ldst[j]);
    }
  };

  f32x4 acc[4][4] = {};

  auto compute = [&](int p) {
    bf16x8 af[4], bfr[4];
#pragma unroll
    for (int t = 0; t < 4; ++t) {
      int ra = wm*64 + t*16 + ml;
      af[t]  = *(const bf16x8*)(&As[p][0] + (size_t)(ra*4 + (kq ^ ((ra >> 1) & 3)))*8);
      int rb = wn*64 + t*16 + ml;
      bfr[t] = *(const bf16x8*)(&Bs[p][0] + (size_t)(rb*4 + (kq ^ ((rb >> 1) & 3)))*8);
    }
#pragma unroll
    for (int i = 0; i < 4; ++i)
#pragma unroll
      for (int j = 0; j < 4; ++j)
        acc[i][j] = __builtin_amdgcn_mfma_f32_16x16x32_bf16(af[i], bfr[j], acc[i][j], 0, 0, 0);
  };

  stage(0, 0);
  for (int k0 = 0; k0 < K; k0 += 64) {
    __syncthreads();
    if (k0 + 32 < K) stage(1, k0 + 32);
    compute(0);
    __syncthreads();
    if (k0 + 64 < K) stage(0, k0 + 64);
    compute(1);
  }

  const float QS = 0.12751747f;                 // (1/sqrt(128)) * log2(e)
#pragma unroll
  for (int i = 0; i < 4; ++i) {
    int rg0 = bm + wm*64 + i*16 + kq*4;
#pragma unroll
    for (int j = 0; j < 4; ++j) {
      int cg = bn + wn*64 + j*16 + ml;
      float bv = bias[cg];
      if (cg < 4096) {                          // q: rope + scale -> qr
        int d = cg & 127, head = cg >> 7;
        float freq = exp2f((float)(d >> 1) * -0.2076205059f);
#pragma unroll
        for (int r = 0; r < 4; ++r) {
          float vb = acc[i][j][r] + bv;
          float pv = __shfl_xor(vb, 1);         // pair partner (cg^1)
          int rg = rg0 + r; int n = rg & 1023; int b = rg >> 10;
          float ang = (float)n * freq;
          float c = cosf(ang), s = sinf(ang);
          float res = (d & 1) ? (vb*c + pv*s) : (vb*c - pv*s);
          qr[(((size_t)(b*32 + head))*1024 + n)*128 + d] = f2bf(res * QS);
        }
      } else if (cg < 4608) {                   // k: rope -> kr
        int c2 = cg - 4096;
        int d = c2 & 127, kvh = c2 >> 7;
        float freq = exp2f((float)(d >> 1) * -0.2076205059f);
#pragma unroll
        for (int r = 0; r < 4; ++r) {
          float vb = acc[i][j][r] + bv;
          float pv = __shfl_xor(vb, 1);
          int rg = rg0 + r; int n = rg & 1023; int b = rg >> 10;
          float ang = (float)n * freq;
          float c = cosf(ang), s = sinf(ang);
          float res = (d & 1) ? (vb*c + pv*s) : (vb*c - pv*s);
          kr[(((size_t)(b*4 + kvh))*1024 + n)*128 + d] = f2bf(res);
        }
      } else {                                  // v: compact vbuf (ld 512)
        int cv = cg - 4608;
#pragma unroll
        for (int r = 0; r < 4; ++r)
          vbuf[(size_t)(rg0 + r)*512 + cv] = f2bf(acc[i][j][r] + bv);
      }
    }
  }
}

// ---------------------------------------------------------------------------
// Flash attention: grid (qt=16, b*32+head=128), block 256 (4 waves x 16 rows).
// Q pre-scaled by (1/sqrt(d))*log2(e); softmax via exp2. Descending qt order.
// Round-4 structure:
//  - Q hoisted to registers (16 VGPR; read once from global, no Qs LDS).
//  - K AND V double-buffered; stage(kt+1) issued at iteration top, then the
//    FULL iteration (QK 16 MFMA + softmax + PV 16 MFMA) runs before the
//    single end-of-iteration __syncthreads drains it. One barrier per
//    iteration (was 2), staging latency fully hidden under compute.
//  - T5 setprio(1) around both MFMA clusters (attn-confirmed +4-7%, m191).
// Buffer safety: iter kt reads buf p=kt&1 (drained at iter kt-1's barrier);
// iter kt+1 stages into buf p only after iter kt's barrier. Ps is a per-wave
// slice written+read by the same wave (compiler-ordered lgkmcnt, no barrier).
// LDS = 32(K) + 32(V) + 9.2(P) = 73.2 KB -> 2 blocks/CU.
// ---------------------------------------------------------------------------
__global__ __launch_bounds__(256)
void attn(const u16* __restrict__ Q, const u16* __restrict__ K,
          const u16* __restrict__ V, u16* __restrict__ ctx) {
  __shared__ __attribute__((aligned(16))) u16 Ks[2][64*128];
  __shared__ __attribute__((aligned(16))) u16 Vs[2][128*64];
  __shared__ __attribute__((aligned(16))) u16 Ps[4][16*72];  // pad 8: conflict-free A-reads
  const int qt  = (int)gridDim.x - 1 - (int)blockIdx.x;
  const int bh  = blockIdx.y;
  const int b   = bh >> 5;
  const int kvh = bh & 3;
  const int tid = threadIdx.x;
  const int lane = tid & 63;
  const int wave = tid >> 6;
  const int kq = lane >> 4, ml = lane & 15;

  const u16* Kg = K + ((size_t)(b*4 + kvh))*1024*128;
  const u16* Vg = V + ((size_t)(b*4 + kvh))*128*1024;

  // Q fragments -> registers. A-frag: row = wave*16+ml, cols ks*32 + kq*8.
  bf16x8 qf[4];
  {
    const u16* Qrow = Q + ((size_t)bh*1024 + qt*64 + wave*16 + ml)*128;
#pragma unroll
    for (int ks = 0; ks < 4; ++ks)
      qf[ks] = *(const bf16x8*)(Qrow + (ks*4 + kq)*8);
  }

  auto stageKV = [&](int kt, int p) {
#pragma unroll
    for (int j = 0; j < 4; ++j) {              // K tile 64x128, slot r*16 + (c ^ (r&7))
      int s = wave*256 + j*64 + lane;
      int r = s >> 4, c = (s & 15) ^ (r & 7);
      gld16(Kg + ((size_t)(kt*64 + r))*128 + c*8, &Ks[p][0] + (size_t)(wave*256 + j*64)*8);
    }
#pragma unroll
    for (int j = 0; j < 4; ++j) {              // V^T tile 128x64, slot d*8 + (c ^ (d&7))
      int s = wave*256 + j*64 + lane;
      int d = s >> 3, c = (s & 7) ^ (d & 7);
      gld16(Vg + (size_t)d*1024 + kt*64 + c*8, &Vs[p][0] + (size_t)(wave*256 + j*64)*8);
    }
  };

  stageKV(0, 0);
  __syncthreads();                             // tile 0 landed

  f32x4 o[8] = {};
  float m_i[4] = {-1e30f, -1e30f, -1e30f, -1e30f};
  float l_i[4] = {0.f, 0.f, 0.f, 0.f};

  for (int kt = 0; kt <= qt; ++kt) {
    const int p = kt & 1;
    if (kt < qt) stageKV(kt + 1, p ^ 1);       // lands under this whole iteration

    // S = Q * K^T  (16 rows x 64 cols per wave)
    f32x4 sf[4] = {};
    __builtin_amdgcn_s_setprio(1);
#pragma unroll
    for (int ks = 0; ks < 4; ++ks) {
#pragma unroll
      for (int nt = 0; nt < 4; ++nt) {
        int rk = nt*16 + ml;
        int cq = ks*4 + kq;
        bf16x8 bk = *(const bf16x8*)(&Ks[p][0] + (size_t)(rk*16 + (cq ^ (rk & 7)))*8);
        sf[nt] = __builtin_amdgcn_mfma_f32_16x16x32_bf16(qf[ks], bk, sf[nt], 0, 0, 0);
      }
    }
    __builtin_amdgcn_s_setprio(0);

    const int i0 = qt*64 + wave*16 + kq*4;     // global q row of reg 0
    if (kt == qt) {                            // causal mask on diagonal tile
#pragma unroll
      for (int nt = 0; nt < 4; ++nt) {
        int jg = kt*64 + nt*16 + ml;
#pragma unroll
        for (int r = 0; r < 4; ++r)
          if (jg > i0 + r) sf[nt][r] = -1e30f;
      }
    }
    float rmax[4] = {-1e30f, -1e30f, -1e30f, -1e30f};
#pragma unroll
    for (int nt = 0; nt < 4; ++nt)
#pragma unroll
      for (int r = 0; r < 4; ++r)
        rmax[r] = fmaxf(rmax[r], sf[nt][r]);
#pragma unroll
    for (int r = 0; r < 4; ++r) {              // row-reduce across the 16 col-lanes
      float v = rmax[r];
      v = fmaxf(v, __shfl_xor(v, 1));
      v = fmaxf(v, __shfl_xor(v, 2));
      v = fmaxf(v, __shfl_xor(v, 4));
      v = fmaxf(v, __shfl_xor(v, 8));
      float mo = m_i[r];
      float mn = fmaxf(mo, v);
      m_i[r] = mn;
      rmax[r] = exp2f(mo - mn);                // alpha
    }
    float rsum[4] = {0.f, 0.f, 0.f, 0.f};
#pragma unroll
    for (int nt = 0; nt < 4; ++nt)
#pragma unroll
      for (int r = 0; r < 4; ++r) {
        float p2 = exp2f(sf[nt][r] - m_i[r]);
        rsum[r] += p2;
        Ps[wave][(kq*4 + r)*72 + nt*16 + ml] = f2bf(p2);
      }
#pragma unroll
    for (int r = 0; r < 4; ++r) {
      float v = rsum[r];
      v += __shfl_xor(v, 1);
      v += __shfl_xor(v, 2);
      v += __shfl_xor(v, 4);
      v += __shfl_xor(v, 8);
      l_i[r] = l_i[r]*rmax[r] + v;
    }
#pragma unroll
    for (int dt = 0; dt < 8; ++dt)
#pragma unroll
      for (int r = 0; r < 4; ++r)
        o[dt][r] *= rmax[r];

    // O += P(16x64) * V(64x128); Ps is own-wave (compiler-ordered)
    __builtin_amdgcn_s_setprio(1);
#pragma unroll
    for (int ks = 0; ks < 2; ++ks) {
      bf16x8 ap = *(const bf16x8*)(&Ps[wave][ml*72 + ks*32 + kq*8]);
#pragma unroll
      for (int dt = 0; dt < 8; ++dt) {
        int dv = dt*16 + ml;
        int cv = ks*4 + kq;
        bf16x8 bv = *(const bf16x8*)(&Vs[p][0] + (size_t)(dv*8 + (cv ^ (dv & 7)))*8);
        o[dt] = __builtin_amdgcn_mfma_f32_16x16x32_bf16(ap, bv, o[dt], 0, 0, 0);
      }
    }
    __builtin_amdgcn_s_setprio(0);

    __syncthreads();                           // staged tile landed; bufs p free
  }

  const int head = bh & 31;
  float inv[4];
#pragma unroll
  for (int r = 0; r < 4; ++r) inv[r] = 1.f / l_i[r];
  size_t row0 = (size_t)b*1024 + qt*64 + wave*16 + kq*4;
#pragma unroll
  for (int dt = 0; dt < 8; ++dt) {
    int cg = head*128 + dt*16 + ml;
#pragma unroll
    for (int r = 0; r < 4; ++r)
      ctx[(row0 + r)*4096 + cg] = f2bf(o[dt][r]*inv[r]);
  }
}

// ---------------------------------------------------------------------------
// prep kernels
// ---------------------------------------------------------------------------
__global__ void castx(const float* __restrict__ x, u16* __restrict__ xb) {
  size_t i = ((size_t)blockIdx.x*256 + threadIdx.x)*4;
  float4 v = *(const float4*)(x + i);
  ushort4 o; o.x = f2bf(v.x); o.y = f2bf(v.y); o.z = f2bf(v.z); o.w = f2bf(v.w);
  *(ushort4*)(xb + i) = o;
}

// W (K,N) f32 -> Wt (N,K) bf16, 64x64 tiles, 256 threads.
// LDS pitch 71 u16: transposed reads are conflict-free.
__global__ void wtrans(const float* __restrict__ W, u16* __restrict__ Wt, int K, int N) {
  __shared__ u16 t[64*71 + 8];
  const int n0 = blockIdx.x*64, k0 = blockIdx.y*64;
  const int tid = threadIdx.x;
  const int kr = tid >> 4, nc = (tid & 15)*4;
#pragma unroll
  for (int i = 0; i < 4; ++i) {
    float4 v = *(const float4*)(W + (size_t)(k0 + kr + i*16)*N + n0 + nc);
    u16* d = &t[(kr + i*16)*71 + nc];
    d[0] = f2bf(v.x); d[1] = f2bf(v.y); d[2] = f2bf(v.z); d[3] = f2bf(v.w);
  }
  __syncthreads();
  const int n = tid >> 2, k16 = (tid & 3)*16;
  u16x8 lo, hi;
#pragma unroll
  for (int j = 0; j < 8; ++j) lo[j] = t[(k16 + j)*71 + n];
#pragma unroll
  for (int j = 0; j < 8; ++j) hi[j] = t[(k16 + 8 + j)*71 + n];
  u16* dst = Wt + (size_t)(n0 + n)*K + k0 + k16;
  *(u16x8*)(dst)     = lo;
  *(u16x8*)(dst + 8) = hi;
}

__global__ void packbias(const float* __restrict__ bq, const float* __restrict__ bk,
                         const float* __restrict__ bv, float* __restrict__ out) {
  int i = blockIdx.x*256 + threadIdx.x;
  float v;
  if (i < 4096)      v = bq[i];
  else if (i < 4608) v = bk[i - 4096];
  else               v = bv[i - 4608];
  out[i] = v;
}

// vbuf (4096 x 512, row = b*1024+n) -> V^T (b, kvh, d=128, n=1024)
__global__ void vtrans(const u16* __restrict__ vbuf, u16* __restrict__ vt) {
  __shared__ u16 t[32][40];
  const int nt = blockIdx.x, dt = blockIdx.y, bk = blockIdx.z;
  const int b = bk >> 2, kvh = bk & 3;
  const int tid = threadIdx.x;
  const int r = tid >> 3, c4 = (tid & 7)*4;
  const u16* src = vbuf + ((size_t)(b*1024 + nt*32 + r))*512 + kvh*128 + dt*32 + c4;
#pragma unroll
  for (int i = 0; i < 4; ++i) t[r][c4 + i] = src[i];
  __syncthreads();
  u16* dst = vt + ((size_t)((b*4 + kvh)*128 + dt*32 + r))*1024 + nt*32 + c4;
#pragma unroll
  for (int i = 0; i < 4; ++i) dst[i] = t[c4 + i][r];
}

// ---------------------------------------------------------------------------
extern "C" void kernel_launch(void* const* d_in, const int* in_sizes, int n_in,
                              void* d_out, int out_size, void* d_ws, size_t ws_size,
                              hipStream_t stream) {
  const float* x  = (const float*)d_in[0];
  const float* Wq = (const float*)d_in[1];
  const float* bq = (const float*)d_in[2];
  const float* Wk = (const float*)d_in[3];
  const float* bk = (const float*)d_in[4];
  const float* Wv = (const float*)d_in[5];
  const float* bv = (const float*)d_in[6];
  const float* Wo = (const float*)d_in[7];
  const float* bo = (const float*)d_in[8];
  float* out = (float*)d_out;

  char* ws = (char*)d_ws;
  u16*   xb   = (u16*)(ws + 0);              // 33.5 MB  (x bf16)
  u16*   wqkv = (u16*)(ws + 33554432);       // 41.9 MB  (Wq^T|Wk^T|Wv^T bf16, 5120x4096)
  u16*   wo_t = (u16*)(ws + 75497472);       // 33.5 MB  (Wo^T bf16)
  float* bqkv = (float*)(ws + 109051904);    // 20 KB    (bq|bk|bv)
  u16*   qr   = (u16*)(ws + 109072384);      // 33.5 MB  (b,h,n,d)  [fresh]
  u16*   kr   = (u16*)(ws + 142626816);      // 4.2 MB   (b,kvh,n,d)[fresh]
  u16*   vbuf = (u16*)(ws + 146821120);      // 4.2 MB   (4096x512) [fresh; end 151015424 = prior footprint]
  // dead-buffer reuse after gemm_qkv:
  u16*   vt   = (u16*)(ws + 33554432);       // over wqkv  (b,kvh,d,n)
  u16*   ctx  = (u16*)(ws + 0);              // over xb    (b*n, 4096)

  castx<<<16384, 256, 0, stream>>>(x, xb);
  wtrans<<<dim3(64,64), 256, 0, stream>>>(Wq, wqkv, 4096, 4096);
  wtrans<<<dim3(8,64),  256, 0, stream>>>(Wk, wqkv + (size_t)4096*4096, 4096, 512);
  wtrans<<<dim3(8,64),  256, 0, stream>>>(Wv, wqkv + (size_t)4608*4096, 4096, 512);
  wtrans<<<dim3(64,64), 256, 0, stream>>>(Wo, wo_t, 4096, 4096);
  packbias<<<20, 256, 0, stream>>>(bq, bk, bv, bqkv);

  gemm_qkv<<<dim3(40,32), 256, 0, stream>>>(xb, wqkv, bqkv, qr, kr, vbuf, 4096);

  vtrans<<<dim3(32,4,16), 256, 0, stream>>>(vbuf, vt);

  attn<<<dim3(16,128), 256, 0, stream>>>(qr, kr, vt, ctx);

  gemm_bt<true><<<dim3(32,32), 256, 0, stream>>>(ctx, wo_t, bo, out, 4096, 4096, 4096);
}

// Round 6
// 827.633 us; speedup vs baseline: 5.0233x; 5.0233x over previous
//
#include <hip/hip_runtime.h>
#include <cstdint>
#include <cstddef>

typedef unsigned short u16;
typedef unsigned int u32;

typedef __bf16 bf16x8 __attribute__((ext_vector_type(8)));
typedef float f32x4 __attribute__((ext_vector_type(4)));
typedef u16 u16x8 __attribute__((ext_vector_type(8)));

__device__ __forceinline__ u16 f2bf(float f) {
  union { float f; u32 u; } v; v.f = f;
  u32 r = v.u + 0x7fffu + ((v.u >> 16) & 1u);   // RNE
  return (u16)(r >> 16);
}
__device__ __forceinline__ float bf2f(u16 h) {
  union { u32 u; float f; } v; v.u = ((u32)h) << 16;
  return v.f;
}

// async global->LDS, 16B per lane; LDS dest = wave-uniform base + lane*16
__device__ __forceinline__ void gld16(const u16* g, u16* l) {
  __builtin_amdgcn_global_load_lds((const __attribute__((address_space(1))) u32*)g,
                                   (__attribute__((address_space(3))) u32*)l,
                                   16, 0, 0);
}

// hw trig, input in REVOLUTIONS (v_sin_f32: D = sin(S0*2pi)); single VALU
// instruction, no OCML call -> no ABI spill of live accumulators (round-5
// lesson: cosf/sinf calls in the epilogue demoted acc to scratch, 15 GB
// of spill traffic, VGPR_Count 44, 3.7 ms).
__device__ __forceinline__ void hw_sincos_rev(float rev, float& s, float& c) {
  rev -= floorf(rev);                       // v_floor + v_sub, inlined
  s = __builtin_amdgcn_sinf(rev);
  c = __builtin_amdgcn_cosf(rev);
}

// ---------------------------------------------------------------------------
// GEMM core (round-0 known-good, MfmaUtil 32%): 128x128 tiles, BK=32,
// double-buffered LDS; prefetch issued right after the barrier, before
// compute. LDS chunk swizzle: chunk(r,c) at slot r*4+(c^((r>>1)&3)) -> 0
// bank conflicts (measured).
// ---------------------------------------------------------------------------
template<bool OUT_F32>
__global__ __launch_bounds__(256)
void gemm_bt(const u16* __restrict__ A, const u16* __restrict__ Bt,
             const float* __restrict__ bias, void* __restrict__ C,
             int M, int N, int K) {
  __shared__ __attribute__((aligned(16))) u16 As[2][128*32];
  __shared__ __attribute__((aligned(16))) u16 Bs[2][128*32];
  const int tid  = threadIdx.x;
  const int lane = tid & 63;
  const int wave = tid >> 6;
  const int wm = wave >> 1, wn = wave & 1;
  const int bn = blockIdx.x * 128;
  const int bm = blockIdx.y * 128;
  const int kq = lane >> 4, ml = lane & 15;

  const u16* agp[2]; const u16* bgp[2]; int ldst[2];
#pragma unroll
  for (int j = 0; j < 2; ++j) {
    int s = wave*128 + j*64 + lane;
    int r = s >> 2;
    int c = (s & 3) ^ ((r >> 1) & 3);
    agp[j] = A  + (size_t)(bm + r)*K + c*8;
    bgp[j] = Bt + (size_t)(bn + r)*K + c*8;
    ldst[j] = (wave*128 + j*64)*8;
  }

  auto stage = [&](int p, int k0) {
#pragma unroll
    for (int j = 0; j < 2; ++j) {
      gld16(agp[j] + k0, &As[p][0] + ldst[j]);
      gld16(bgp[j] + k0, &Bs[p][0] + ldst[j]);
    }
  };

  f32x4 acc[4][4] = {};

  auto compute = [&](int p) {
    bf16x8 af[4], bfr[4];
#pragma unroll
    for (int t = 0; t < 4; ++t) {
      int ra = wm*64 + t*16 + ml;
      af[t]  = *(const bf16x8*)(&As[p][0] + (size_t)(ra*4 + (kq ^ ((ra >> 1) & 3)))*8);
      int rb = wn*64 + t*16 + ml;
      bfr[t] = *(const bf16x8*)(&Bs[p][0] + (size_t)(rb*4 + (kq ^ ((rb >> 1) & 3)))*8);
    }
#pragma unroll
    for (int i = 0; i < 4; ++i)
#pragma unroll
      for (int j = 0; j < 4; ++j)
        acc[i][j] = __builtin_amdgcn_mfma_f32_16x16x32_bf16(af[i], bfr[j], acc[i][j], 0, 0, 0);
  };

  stage(0, 0);
  for (int k0 = 0; k0 < K; k0 += 64) {          // K multiple of 64
    __syncthreads();
    if (k0 + 32 < K) stage(1, k0 + 32);
    compute(0);
    __syncthreads();
    if (k0 + 64 < K) stage(0, k0 + 64);
    compute(1);
  }

  // C/D layout: col = lane&15, row = (lane>>4)*4 + reg   [m89/m91 verified]
#pragma unroll
  for (int i = 0; i < 4; ++i) {
    int rg0 = bm + wm*64 + i*16 + kq*4;
#pragma unroll
    for (int j = 0; j < 4; ++j) {
      int cg = bn + wn*64 + j*16 + ml;
      float bv = bias[cg];
#pragma unroll
      for (int r = 0; r < 4; ++r) {
        float v = acc[i][j][r] + bv;
        if (OUT_F32) ((float*)C)[(size_t)(rg0 + r)*N + cg] = v;
        else         ((u16*)C)[(size_t)(rg0 + r)*N + cg]   = f2bf(v);
      }
    }
  }
}

// ---------------------------------------------------------------------------
// QKV GEMM with FUSED RoPE epilogue (hw v_sin/v_cos, no calls -> no spill).
// Same main loop as gemm_bt (M=4096, N=5120, K=4096). Epilogue routes by
// block-uniform bn region (4096 and 4608 are multiples of 128):
//   cg <  4096 : q -> rope -> *QS -> qr (b,head,n,d)
//   cg <  4608 : k -> rope -> kr (b,kvh,n,d)
//   else       : v -> vbuf (4096 x 512, compact)
// RoPE pair partner (cg^1) sits in lane ml^1 -> __shfl_xor(v,1); both lanes
// of a pair use the same angle (dp = d>>1). Bias added BEFORE rope.
// Angle in revolutions: rev = n * exp2(dp*-0.2076..)/(2pi); fract-reduced.
// ---------------------------------------------------------------------------
__global__ __launch_bounds__(256, 2)
void gemm_qkv(const u16* __restrict__ A, const u16* __restrict__ Bt,
              const float* __restrict__ bias, u16* __restrict__ qr,
              u16* __restrict__ kr, u16* __restrict__ vbuf, int K) {
  __shared__ __attribute__((aligned(16))) u16 As[2][128*32];
  __shared__ __attribute__((aligned(16))) u16 Bs[2][128*32];
  const int tid  = threadIdx.x;
  const int lane = tid & 63;
  const int wave = tid >> 6;
  const int wm = wave >> 1, wn = wave & 1;
  const int bn = blockIdx.x * 128;
  const int bm = blockIdx.y * 128;
  const int kq = lane >> 4, ml = lane & 15;

  const u16* agp[2]; const u16* bgp[2]; int ldst[2];
#pragma unroll
  for (int j = 0; j < 2; ++j) {
    int s = wave*128 + j*64 + lane;
    int r = s >> 2;
    int c = (s & 3) ^ ((r >> 1) & 3);
    agp[j] = A  + (size_t)(bm + r)*K + c*8;
    bgp[j] = Bt + (size_t)(bn + r)*K + c*8;
    ldst[j] = (wave*128 + j*64)*8;
  }

  auto stage = [&](int p, int k0) {
#pragma unroll
    for (int j = 0; j < 2; ++j) {
      gld16(agp[j] + k0, &As[p][0] + ldst[j]);
      gld16(bgp[j] + k0, &Bs[p][0] + ldst[j]);
    }
  };

  f32x4 acc[4][4] = {};

  auto compute = [&](int p) {
    bf16x8 af[4], bfr[4];
#pragma unroll
    for (int t = 0; t < 4; ++t) {
      int ra = wm*64 + t*16 + ml;
      af[t]  = *(const bf16x8*)(&As[p][0] + (size_t)(ra*4 + (kq ^ ((ra >> 1) & 3)))*8);
      int rb = wn*64 + t*16 + ml;
      bfr[t] = *(const bf16x8*)(&Bs[p][0] + (size_t)(rb*4 + (kq ^ ((rb >> 1) & 3)))*8);
    }
#pragma unroll
    for (int i = 0; i < 4; ++i)
#pragma unroll
      for (int j = 0; j < 4; ++j)
        acc[i][j] = __builtin_amdgcn_mfma_f32_16x16x32_bf16(af[i], bfr[j], acc[i][j], 0, 0, 0);
  };

  stage(0, 0);
  for (int k0 = 0; k0 < K; k0 += 64) {
    __syncthreads();
    if (k0 + 32 < K) stage(1, k0 + 32);
    compute(0);
    __syncthreads();
    if (k0 + 64 < K) stage(0, k0 + 64);
    compute(1);
  }

  const float QS    = 0.12751747f;              // (1/sqrt(128)) * log2(e)
  const float R2PI  = 0.15915494f;              // 1/(2*pi)
#pragma unroll
  for (int i = 0; i < 4; ++i) {
    int rg0 = bm + wm*64 + i*16 + kq*4;
#pragma unroll
    for (int j = 0; j < 4; ++j) {
      int cg = bn + wn*64 + j*16 + ml;
      float bv = bias[cg];
      if (cg < 4096) {                          // q: rope + scale -> qr
        int d = cg & 127, head = cg >> 7;
        float frev = __builtin_amdgcn_exp2f((float)(d >> 1) * -0.2076205059f) * R2PI;
#pragma unroll
        for (int r = 0; r < 4; ++r) {
          float vb = acc[i][j][r] + bv;
          float pv = __shfl_xor(vb, 1);         // pair partner (cg^1)
          int rg = rg0 + r; int n = rg & 1023; int b = rg >> 10;
          float s, c; hw_sincos_rev((float)n * frev, s, c);
          float res = (d & 1) ? (vb*c + pv*s) : (vb*c - pv*s);
          qr[(((size_t)(b*32 + head))*1024 + n)*128 + d] = f2bf(res * QS);
        }
      } else if (cg < 4608) {                   // k: rope -> kr
        int c2 = cg - 4096;
        int d = c2 & 127, kvh = c2 >> 7;
        float frev = __builtin_amdgcn_exp2f((float)(d >> 1) * -0.2076205059f) * R2PI;
#pragma unroll
        for (int r = 0; r < 4; ++r) {
          float vb = acc[i][j][r] + bv;
          float pv = __shfl_xor(vb, 1);
          int rg = rg0 + r; int n = rg & 1023; int b = rg >> 10;
          float s, c; hw_sincos_rev((float)n * frev, s, c);
          float res = (d & 1) ? (vb*c + pv*s) : (vb*c - pv*s);
          kr[(((size_t)(b*4 + kvh))*1024 + n)*128 + d] = f2bf(res);
        }
      } else {                                  // v: compact vbuf (ld 512)
        int cv = cg - 4608;
#pragma unroll
        for (int r = 0; r < 4; ++r)
          vbuf[(size_t)(rg0 + r)*512 + cv] = f2bf(acc[i][j][r] + bv);
      }
    }
  }
}

// ---------------------------------------------------------------------------
// Flash attention: grid (qt=16, b*32+head=128), block 256 (4 waves x 16 rows).
// Q pre-scaled by (1/sqrt(d))*log2(e); softmax via exp2. Descending qt order.
// Round-4 structure (kept): Q hoisted to registers; K AND V double-buffered;
// stage(kt+1) at iteration top, full iteration of compute before the single
// end-of-iteration __syncthreads drains it. T5 setprio around MFMA clusters.
// LDS = 32(K) + 32(V) + 9.2(P) = 73.2 KB -> 2 blocks/CU.
// ---------------------------------------------------------------------------
__global__ __launch_bounds__(256)
void attn(const u16* __restrict__ Q, const u16* __restrict__ K,
          const u16* __restrict__ V, u16* __restrict__ ctx) {
  __shared__ __attribute__((aligned(16))) u16 Ks[2][64*128];
  __shared__ __attribute__((aligned(16))) u16 Vs[2][128*64];
  __shared__ __attribute__((aligned(16))) u16 Ps[4][16*72];  // pad 8: conflict-free A-reads
  const int qt  = (int)gridDim.x - 1 - (int)blockIdx.x;
  const int bh  = blockIdx.y;
  const int b   = bh >> 5;
  const int kvh = bh & 3;
  const int tid = threadIdx.x;
  const int lane = tid & 63;
  const int wave = tid >> 6;
  const int kq = lane >> 4, ml = lane & 15;

  const u16* Kg = K + ((size_t)(b*4 + kvh))*1024*128;
  const u16* Vg = V + ((size_t)(b*4 + kvh))*128*1024;

  // Q fragments -> registers. A-frag: row = wave*16+ml, cols ks*32 + kq*8.
  bf16x8 qf[4];
  {
    const u16* Qrow = Q + ((size_t)bh*1024 + qt*64 + wave*16 + ml)*128;
#pragma unroll
    for (int ks = 0; ks < 4; ++ks)
      qf[ks] = *(const bf16x8*)(Qrow + (ks*4 + kq)*8);
  }

  auto stageKV = [&](int kt, int p) {
#pragma unroll
    for (int j = 0; j < 4; ++j) {              // K tile 64x128, slot r*16 + (c ^ (r&7))
      int s = wave*256 + j*64 + lane;
      int r = s >> 4, c = (s & 15) ^ (r & 7);
      gld16(Kg + ((size_t)(kt*64 + r))*128 + c*8, &Ks[p][0] + (size_t)(wave*256 + j*64)*8);
    }
#pragma unroll
    for (int j = 0; j < 4; ++j) {              // V^T tile 128x64, slot d*8 + (c ^ (d&7))
      int s = wave*256 + j*64 + lane;
      int d = s >> 3, c = (s & 7) ^ (d & 7);
      gld16(Vg + (size_t)d*1024 + kt*64 + c*8, &Vs[p][0] + (size_t)(wave*256 + j*64)*8);
    }
  };

  stageKV(0, 0);
  __syncthreads();                             // tile 0 landed

  f32x4 o[8] = {};
  float m_i[4] = {-1e30f, -1e30f, -1e30f, -1e30f};
  float l_i[4] = {0.f, 0.f, 0.f, 0.f};

  for (int kt = 0; kt <= qt; ++kt) {
    const int p = kt & 1;
    if (kt < qt) stageKV(kt + 1, p ^ 1);       // lands under this whole iteration

    // S = Q * K^T  (16 rows x 64 cols per wave)
    f32x4 sf[4] = {};
    __builtin_amdgcn_s_setprio(1);
#pragma unroll
    for (int ks = 0; ks < 4; ++ks) {
#pragma unroll
      for (int nt = 0; nt < 4; ++nt) {
        int rk = nt*16 + ml;
        int cq = ks*4 + kq;
        bf16x8 bk = *(const bf16x8*)(&Ks[p][0] + (size_t)(rk*16 + (cq ^ (rk & 7)))*8);
        sf[nt] = __builtin_amdgcn_mfma_f32_16x16x32_bf16(qf[ks], bk, sf[nt], 0, 0, 0);
      }
    }
    __builtin_amdgcn_s_setprio(0);

    const int i0 = qt*64 + wave*16 + kq*4;     // global q row of reg 0
    if (kt == qt) {                            // causal mask on diagonal tile
#pragma unroll
      for (int nt = 0; nt < 4; ++nt) {
        int jg = kt*64 + nt*16 + ml;
#pragma unroll
        for (int r = 0; r < 4; ++r)
          if (jg > i0 + r) sf[nt][r] = -1e30f;
      }
    }
    float rmax[4] = {-1e30f, -1e30f, -1e30f, -1e30f};
#pragma unroll
    for (int nt = 0; nt < 4; ++nt)
#pragma unroll
      for (int r = 0; r < 4; ++r)
        rmax[r] = fmaxf(rmax[r], sf[nt][r]);
#pragma unroll
    for (int r = 0; r < 4; ++r) {              // row-reduce across the 16 col-lanes
      float v = rmax[r];
      v = fmaxf(v, __shfl_xor(v, 1));
      v = fmaxf(v, __shfl_xor(v, 2));
      v = fmaxf(v, __shfl_xor(v, 4));
      v = fmaxf(v, __shfl_xor(v, 8));
      float mo = m_i[r];
      float mn = fmaxf(mo, v);
      m_i[r] = mn;
      rmax[r] = exp2f(mo - mn);                // alpha
    }
    float rsum[4] = {0.f, 0.f, 0.f, 0.f};
#pragma unroll
    for (int nt = 0; nt < 4; ++nt)
#pragma unroll
      for (int r = 0; r < 4; ++r) {
        float p2 = exp2f(sf[nt][r] - m_i[r]);
        rsum[r] += p2;
        Ps[wave][(kq*4 + r)*72 + nt*16 + ml] = f2bf(p2);
      }
#pragma unroll
    for (int r = 0; r < 4; ++r) {
      float v = rsum[r];
      v += __shfl_xor(v, 1);
      v += __shfl_xor(v, 2);
      v += __shfl_xor(v, 4);
      v += __shfl_xor(v, 8);
      l_i[r] = l_i[r]*rmax[r] + v;
    }
#pragma unroll
    for (int dt = 0; dt < 8; ++dt)
#pragma unroll
      for (int r = 0; r < 4; ++r)
        o[dt][r] *= rmax[r];

    // O += P(16x64) * V(64x128); Ps is own-wave (compiler-ordered)
    __builtin_amdgcn_s_setprio(1);
#pragma unroll
    for (int ks = 0; ks < 2; ++ks) {
      bf16x8 ap = *(const bf16x8*)(&Ps[wave][ml*72 + ks*32 + kq*8]);
#pragma unroll
      for (int dt = 0; dt < 8; ++dt) {
        int dv = dt*16 + ml;
        int cv = ks*4 + kq;
        bf16x8 bv = *(const bf16x8*)(&Vs[p][0] + (size_t)(dv*8 + (cv ^ (dv & 7)))*8);
        o[dt] = __builtin_amdgcn_mfma_f32_16x16x32_bf16(ap, bv, o[dt], 0, 0, 0);
      }
    }
    __builtin_amdgcn_s_setprio(0);

    __syncthreads();                           // staged tile landed; bufs p free
  }

  const int head = bh & 31;
  float inv[4];
#pragma unroll
  for (int r = 0; r < 4; ++r) inv[r] = 1.f / l_i[r];
  size_t row0 = (size_t)b*1024 + qt*64 + wave*16 + kq*4;
#pragma unroll
  for (int dt = 0; dt < 8; ++dt) {
    int cg = head*128 + dt*16 + ml;
#pragma unroll
    for (int r = 0; r < 4; ++r)
      ctx[(row0 + r)*4096 + cg] = f2bf(o[dt][r]*inv[r]);
  }
}

// ---------------------------------------------------------------------------
// prep kernels
// ---------------------------------------------------------------------------
__global__ void castx(const float* __restrict__ x, u16* __restrict__ xb) {
  size_t i = ((size_t)blockIdx.x*256 + threadIdx.x)*4;
  float4 v = *(const float4*)(x + i);
  ushort4 o; o.x = f2bf(v.x); o.y = f2bf(v.y); o.z = f2bf(v.z); o.w = f2bf(v.w);
  *(ushort4*)(xb + i) = o;
}

// W (K,N) f32 -> Wt (N,K) bf16, 64x64 tiles, 256 threads.
// LDS pitch 71 u16: transposed reads are conflict-free.
__global__ void wtrans(const float* __restrict__ W, u16* __restrict__ Wt, int K, int N) {
  __shared__ u16 t[64*71 + 8];
  const int n0 = blockIdx.x*64, k0 = blockIdx.y*64;
  const int tid = threadIdx.x;
  const int kr = tid >> 4, nc = (tid & 15)*4;
#pragma unroll
  for (int i = 0; i < 4; ++i) {
    float4 v = *(const float4*)(W + (size_t)(k0 + kr + i*16)*N + n0 + nc);
    u16* d = &t[(kr + i*16)*71 + nc];
    d[0] = f2bf(v.x); d[1] = f2bf(v.y); d[2] = f2bf(v.z); d[3] = f2bf(v.w);
  }
  __syncthreads();
  const int n = tid >> 2, k16 = (tid & 3)*16;
  u16x8 lo, hi;
#pragma unroll
  for (int j = 0; j < 8; ++j) lo[j] = t[(k16 + j)*71 + n];
#pragma unroll
  for (int j = 0; j < 8; ++j) hi[j] = t[(k16 + 8 + j)*71 + n];
  u16* dst = Wt + (size_t)(n0 + n)*K + k0 + k16;
  *(u16x8*)(dst)     = lo;
  *(u16x8*)(dst + 8) = hi;
}

__global__ void packbias(const float* __restrict__ bq, const float* __restrict__ bk,
                         const float* __restrict__ bv, float* __restrict__ out) {
  int i = blockIdx.x*256 + threadIdx.x;
  float v;
  if (i < 4096)      v = bq[i];
  else if (i < 4608) v = bk[i - 4096];
  else               v = bv[i - 4608];
  out[i] = v;
}

// vbuf (4096 x 512, row = b*1024+n) -> V^T (b, kvh, d=128, n=1024)
__global__ void vtrans(const u16* __restrict__ vbuf, u16* __restrict__ vt) {
  __shared__ u16 t[32][40];
  const int nt = blockIdx.x, dt = blockIdx.y, bk = blockIdx.z;
  const int b = bk >> 2, kvh = bk & 3;
  const int tid = threadIdx.x;
  const int r = tid >> 3, c4 = (tid & 7)*4;
  const u16* src = vbuf + ((size_t)(b*1024 + nt*32 + r))*512 + kvh*128 + dt*32 + c4;
#pragma unroll
  for (int i = 0; i < 4; ++i) t[r][c4 + i] = src[i];
  __syncthreads();
  u16* dst = vt + ((size_t)((b*4 + kvh)*128 + dt*32 + r))*1024 + nt*32 + c4;
#pragma unroll
  for (int i = 0; i < 4; ++i) dst[i] = t[c4 + i][r];
}

// ---------------------------------------------------------------------------
extern "C" void kernel_launch(void* const* d_in, const int* in_sizes, int n_in,
                              void* d_out, int out_size, void* d_ws, size_t ws_size,
                              hipStream_t stream) {
  const float* x  = (const float*)d_in[0];
  const float* Wq = (const float*)d_in[1];
  const float* bq = (const float*)d_in[2];
  const float* Wk = (const float*)d_in[3];
  const float* bk = (const float*)d_in[4];
  const float* Wv = (const float*)d_in[5];
  const float* bv = (const float*)d_in[6];
  const float* Wo = (const float*)d_in[7];
  const float* bo = (const float*)d_in[8];
  float* out = (float*)d_out;

  char* ws = (char*)d_ws;
  u16*   xb   = (u16*)(ws + 0);              // 33.5 MB  (x bf16)
  u16*   wqkv = (u16*)(ws + 33554432);       // 41.9 MB  (Wq^T|Wk^T|Wv^T bf16, 5120x4096)
  u16*   wo_t = (u16*)(ws + 75497472);       // 33.5 MB  (Wo^T bf16)
  float* bqkv = (float*)(ws + 109051904);    // 20 KB    (bq|bk|bv)
  u16*   qr   = (u16*)(ws + 109072384);      // 33.5 MB  (b,h,n,d)  [fresh]
  u16*   kr   = (u16*)(ws + 142626816);      // 4.2 MB   (b,kvh,n,d)[fresh]
  u16*   vbuf = (u16*)(ws + 146821120);      // 4.2 MB   (4096x512) [fresh]
  // dead-buffer reuse after gemm_qkv:
  u16*   vt   = (u16*)(ws + 33554432);       // over wqkv  (b,kvh,d,n)
  u16*   ctx  = (u16*)(ws + 0);              // over xb    (b*n, 4096)

  castx<<<16384, 256, 0, stream>>>(x, xb);
  wtrans<<<dim3(64,64), 256, 0, stream>>>(Wq, wqkv, 4096, 4096);
  wtrans<<<dim3(8,64),  256, 0, stream>>>(Wk, wqkv + (size_t)4096*4096, 4096, 512);
  wtrans<<<dim3(8,64),  256, 0, stream>>>(Wv, wqkv + (size_t)4608*4096, 4096, 512);
  wtrans<<<dim3(64,64), 256, 0, stream>>>(Wo, wo_t, 4096, 4096);
  packbias<<<20, 256, 0, stream>>>(bq, bk, bv, bqkv);

  gemm_qkv<<<dim3(40,32), 256, 0, stream>>>(xb, wqkv, bqkv, qr, kr, vbuf, 4096);

  vtrans<<<dim3(32,4,16), 256, 0, stream>>>(vbuf, vt);

  attn<<<dim3(16,128), 256, 0, stream>>>(qr, kr, vt, ctx);

  gemm_bt<true><<<dim3(32,32), 256, 0, stream>>>(ctx, wo_t, bo, out, 4096, 4096, 4096);
}